// Round 5
// baseline (471.660 us; speedup 1.0000x reference)
//
#include <hip/hip_runtime.h>
#include <hip/hip_bf16.h>
#include <math.h>

typedef __attribute__((ext_vector_type(4))) float  f32x4;
typedef __attribute__((ext_vector_type(8))) __bf16 bf16x8;
typedef __attribute__((ext_vector_type(4))) unsigned int u32x4;

__device__ __forceinline__ unsigned short f2bu(float x) {
    __bf16 h = (__bf16)x;
    return __builtin_bit_cast(unsigned short, h);
}

__device__ __forceinline__ f32x4 MF(bf16x8 a, bf16x8 b, f32x4 c) {
    return __builtin_amdgcn_mfma_f32_16x16x32_bf16(a, b, c, 0, 0, 0);
}

__device__ __forceinline__ f32x4 zero4() { f32x4 z = {0.f, 0.f, 0.f, 0.f}; return z; }

// B-fragment (BT row-major, contiguous K): lane holds BT[row][k0..k0+7], f32 -> bf16
__device__ __forceinline__ bf16x8 bfrag_g(const float* W, int ldk, int row, int k0) {
    const float* p = W + (size_t)row * ldk + k0;
    bf16x8 r;
#pragma unroll
    for (int e = 0; e < 8; ++e) r[e] = (__bf16)p[e];
    return r;
}

// ---- LDS layout (bytes), M=32 atoms/tile, two ping-pong bf16 sets + V f32 stage ----
// per set: VIN 3*32*256 = 24576 ; H 32*512 = 16384  -> SET_SZ 40960
#define SET_SZ   40960
#define VIN_OFF  0
#define H_OFF    24576
#define S1_OFF   81920   // 32*256 = 8192
#define RED_OFF  90112   // 8 waves * 32 f32 = 1024
#define VSTG     91136   // V f32 stage: 32*384*4 = 49152
#define LDS_BYTES 140288

// A-fragment read from swizzled LDS tile
__device__ __forceinline__ bf16x8 afrag(const unsigned char* base, int rb, int row, int kb) {
    u32x4 q = *(const u32x4*)(base + row * rb + (kb ^ ((row & 7) << 4)));
    return __builtin_bit_cast(bf16x8, q);
}

__device__ __forceinline__ unsigned long long pack4bf(f32x4 x) {
    return (unsigned long long)f2bu(x[0])
         | ((unsigned long long)f2bu(x[1]) << 16)
         | ((unsigned long long)f2bu(x[2]) << 32)
         | ((unsigned long long)f2bu(x[3]) << 48);
}

// DMA tile t's V (f32, 48KB) into the LDS staging area. Zero VGPR cost.
// LDS dest: wave-uniform base + lane*16 (HW rule); global src per-lane, coalesced.
__device__ __forceinline__ void issue_dma_v(const float* __restrict__ V,
                                            int t, int tid, int wv,
                                            unsigned char* lds) {
    const float* vsrc = V + (size_t)t * (32 * 384);
#pragma unroll
    for (int j = 0; j < 6; ++j)
        __builtin_amdgcn_global_load_lds((const void*)(vsrc + ((tid + (j << 9)) << 2)),
                                         (void*)(lds + VSTG + (j << 13) + (wv << 10)),
                                         16, 0, 0);
}

// Convert staged f32 V tile -> swizzled bf16 VIN in dstSet.
__device__ __forceinline__ void cvt_v(unsigned char* lds, unsigned char* dstSet, int tid) {
#pragma unroll
    for (int j = 0; j < 6; ++j) {
        int c = tid + (j << 9);
        f32x4 x = *(const f32x4*)(lds + VSTG + (c << 4));
        int row = c / 96, rem = c - row * 96;
        int d = rem >> 5, c4 = rem & 31;
        *(unsigned long long*)(dstSet + VIN_OFF + (d << 13) + row * 256 +
                               ((c4 << 3) ^ ((row & 7) << 4))) = pack4bf(x);
    }
}

__global__ __launch_bounds__(512, 2) void eqsc_main(
    const float* __restrict__ S, const float* __restrict__ V,
    const float* __restrict__ u0w, const float* __restrict__ v0w,
    const float* __restrict__ a0w1, const float* __restrict__ a0b1,
    const float* __restrict__ a0w2, const float* __restrict__ a0b2,
    const float* __restrict__ u1w, const float* __restrict__ v1w,
    const float* __restrict__ a1w1, const float* __restrict__ a1b1,
    const float* __restrict__ a1w2, const float* __restrict__ a1b2,
    const float* __restrict__ outw, const float* __restrict__ outbp,
    float* __restrict__ sOut, int NT)
{
    __shared__ __align__(16) unsigned char lds[LDS_BYTES];
    const int tid  = threadIdx.x;
    const int lane = tid & 63;
    const int wv   = tid >> 6;
    const int l15  = lane & 15;
    const int lg   = lane >> 4;
    const int grow = wv * 16 + l15;   // this wave/lane's output feature column
    const int kbb  = lg << 4;         // k-byte base within a 64B kt chunk

    // ---- folded readout: wfold[k] = sum_g a1w2[g,k]*outw[g]; cfold = b2g1.outw + outb
    float wf = 0.f, cf = 0.f;
    for (int g = 0; g < 128; ++g) {
        float og = outw[g];
        wf += a1w2[g * 128 + grow] * og;
        cf += a1b2[g] * og;
    }
    cf += outbp[0];

    // ---- persistent weight fragments (bf16, register-resident): 144 VGPRs ----
    bf16x8 uw0f[4], vw0f[4], w2g0[4], w2s0[4], vw1f[4];
    bf16x8 w1f0[8], w1f1[8];
#pragma unroll
    for (int kt = 0; kt < 4; ++kt) {
        int k0 = kt * 32 + lg * 8;
        uw0f[kt] = bfrag_g(u0w, 128, grow, k0);
        vw0f[kt] = bfrag_g(v0w, 128, grow, k0);
        w2g0[kt] = bfrag_g(a0w2, 128, grow, k0);
        w2s0[kt] = bfrag_g(a0w2, 128, 128 + grow, k0);
        vw1f[kt] = bfrag_g(v1w, 128, grow, k0);
    }
#pragma unroll
    for (int kt = 0; kt < 8; ++kt) {
        int k0 = kt * 32 + lg * 8;
        w1f0[kt] = bfrag_g(a0w1, 256, grow, k0);
        w1f1[kt] = bfrag_g(a1w1, 256, grow, k0);
    }
    const float b1_0 = a0b1[grow];
    const float b2g0 = a0b2[grow];
    const float b2s0 = a0b2[128 + grow];
    const float b1_1 = a1b1[grow];

    const int stride = gridDim.x;
    const int t0 = blockIdx.x;

    // ---- prologue ----
    if (t0 < NT) {
        issue_dma_v(V, t0, tid, wv, lds);                    // V(t0) -> stage
        f32x4 s0a, s0b;
        { int c = tid;       s0a = *(const f32x4*)(S + (size_t)t0 * 4096 + (c << 2)); }
        { int c = tid + 512; s0b = *(const f32x4*)(S + (size_t)t0 * 4096 + (c << 2)); }
        __syncthreads();                                     // drains DMA-V(t0)
        cvt_v(lds, lds, tid);                                // stage -> set0.VIN
        { int c = tid, row = c >> 5, c4 = c & 31;
          *(unsigned long long*)(lds + H_OFF + row * 512 +
                                 ((c4 << 3) ^ ((row & 7) << 4))) = pack4bf(s0a); }
        { int c = tid + 512; int row = c >> 5, c4 = c & 31;
          *(unsigned long long*)(lds + H_OFF + row * 512 +
                                 ((c4 << 3) ^ ((row & 7) << 4))) = pack4bf(s0b); }
        __syncthreads();                                     // cvt reads drained
        if (t0 + stride < NT) issue_dma_v(V, t0 + stride, tid, wv, lds);
    } else {
        __syncthreads(); __syncthreads();
    }
    __syncthreads();

    int i = 0;
    for (int ty = t0; ty < NT + stride; ty += stride, ++i) {
        const bool yv = (ty < NT);
        const bool xv = (i > 0);
        const int  tz = ty + stride;
        const bool zv = (tz < NT);
        const bool z2v = (tz + stride < NT);
        unsigned char* Lsy = lds + (i & 1) * SET_SZ;
        unsigned char* Lsx = lds + ((i & 1) ^ 1) * SET_SZ;

        // ======== slot 1: load S(Z) regs ; Y.P1 (L0 v-phase) || X.P4 (L1 v-phase) ========
        f32x4 sza, szb;
        if (zv) {
            const float* ssrc = S + (size_t)tz * 4096;
            sza = *(const f32x4*)(ssrc + (tid << 2));
            szb = *(const f32x4*)(ssrc + ((tid + 512) << 2));
        }

        f32x4 v1a[2][3];
        if (yv) {
#pragma unroll
            for (int m = 0; m < 2; ++m) {
                const int mr = m << 4;
                f32x4 n2 = zero4();
#pragma unroll
                for (int d = 0; d < 3; ++d) {
                    f32x4 a1 = zero4(), a2 = zero4();
#pragma unroll
                    for (int kt = 0; kt < 4; ++kt) {
                        bf16x8 a = afrag(Lsy + VIN_OFF + (d << 13), 256, mr + l15, (kt << 6) + kbb);
                        a1 = MF(a, uw0f[kt], a1);
                        a2 = MF(a, vw0f[kt], a2);
                    }
                    v1a[m][d] = a1;
#pragma unroll
                    for (int e = 0; e < 4; ++e) { float x = a2[e] + 1e-8f; n2[e] += x * x; }
                }
#pragma unroll
                for (int e = 0; e < 4; ++e) {
                    int row = mr + (lg << 2) + e;
                    *(unsigned short*)(Lsy + H_OFF + row * 512 +
                        ((256 + (grow << 1)) ^ ((row & 7) << 4))) = f2bu(sqrtf(n2[e]));
                }
            }
        }
        if (xv) {
#pragma unroll
            for (int m = 0; m < 2; ++m) {
                const int mr = m << 4;
                f32x4 n2 = zero4();
#pragma unroll
                for (int d = 0; d < 3; ++d) {
                    f32x4 acc = zero4();
#pragma unroll
                    for (int kt = 0; kt < 4; ++kt)
                        acc = MF(afrag(Lsx + VIN_OFF + (d << 13), 256, mr + l15, (kt << 6) + kbb),
                                 vw1f[kt], acc);
#pragma unroll
                    for (int e = 0; e < 4; ++e) { float x = acc[e] + 1e-8f; n2[e] += x * x; }
                }
#pragma unroll
                for (int e = 0; e < 4; ++e) {
                    int row = mr + (lg << 2) + e;
                    *(unsigned short*)(Lsx + H_OFF + row * 512 +
                        ((256 + (grow << 1)) ^ ((row & 7) << 4))) = f2bu(sqrtf(n2[e]));
                }
            }
        }
        __syncthreads();   // drains DMA-V(Z) (issued last slot 3 / prologue)

        // ======== slot 2: Y.P2 (L0 MLP1) || X.P5 (L1 MLP1 + folded readout) ; cvt V(Z)->Lsx ========
        if (yv) {
#pragma unroll
            for (int m = 0; m < 2; ++m) {
                const int mr = m << 4;
                f32x4 acc = zero4();
#pragma unroll
                for (int kt = 0; kt < 8; ++kt)
                    acc = MF(afrag(Lsy + H_OFF, 512, mr + l15, (kt << 6) + kbb), w1f0[kt], acc);
#pragma unroll
                for (int e = 0; e < 4; ++e) {
                    float x = acc[e] + b1_0;
                    float y = x / (1.f + __expf(-x));
                    int row = mr + (lg << 2) + e;
                    *(unsigned short*)(lds + S1_OFF + row * 256 +
                        ((grow << 1) ^ ((row & 7) << 4))) = f2bu(y);
                }
            }
        }
        if (xv) {
#pragma unroll
            for (int m = 0; m < 2; ++m) {
                const int mr = m << 4;
                f32x4 acc = zero4();
#pragma unroll
                for (int kt = 0; kt < 8; ++kt)
                    acc = MF(afrag(Lsx + H_OFF, 512, mr + l15, (kt << 6) + kbb), w1f1[kt], acc);
                float p[4];
#pragma unroll
                for (int e = 0; e < 4; ++e) {
                    float x = acc[e] + b1_1;
                    float y = x / (1.f + __expf(-x));
                    p[e] = y * wf;                 // folded (w2g1^T @ outw) readout, f32
                }
#pragma unroll
                for (int off = 1; off < 16; off <<= 1) {
#pragma unroll
                    for (int e = 0; e < 4; ++e) p[e] += __shfl_xor(p[e], off);
                }
                if (l15 == 0) {
#pragma unroll
                    for (int e = 0; e < 4; ++e)
                        *((float*)(lds + RED_OFF) + (wv << 5) + mr + (lg << 2) + e) = p[e];
                }
            }
        }
        if (zv) cvt_v(lds, Lsx, tid);   // P4-X done with Lsx.VIN (slot 1)
        __syncthreads();

        // ======== slot 3: Y.P3 (L0 MLP2 + v'=v1*ss) ; DMA V(Z2) ; write S(Z)->Lsx ; sOut(X) ========
        if (z2v) issue_dma_v(V, tz + stride, tid, wv, lds);  // stage free (cvt drained)
        if (yv) {
#pragma unroll
            for (int m = 0; m < 2; ++m) {
                const int mr = m << 4;
                f32x4 sg = zero4(), ssa = zero4();
#pragma unroll
                for (int kt = 0; kt < 4; ++kt) {
                    bf16x8 a = afrag(lds + S1_OFF, 256, mr + l15, (kt << 6) + kbb);
                    sg  = MF(a, w2g0[kt], sg);
                    ssa = MF(a, w2s0[kt], ssa);
                }
#pragma unroll
                for (int e = 0; e < 4; ++e) {
                    int row = mr + (lg << 2) + e;
                    int swz = (row & 7) << 4;
                    *(unsigned short*)(Lsy + H_OFF + row * 512 + ((grow << 1) ^ swz)) = f2bu(sg[e] + b2g0);
                    float ssv = ssa[e] + b2s0;
#pragma unroll
                    for (int d = 0; d < 3; ++d)
                        *(unsigned short*)(Lsy + VIN_OFF + (d << 13) + row * 256 +
                            ((grow << 1) ^ swz)) = f2bu(v1a[m][d][e] * ssv);
                }
            }
        }
        if (zv) {
            { int c = tid, row = c >> 5, c4 = c & 31;
              *(unsigned long long*)(Lsx + H_OFF + row * 512 +
                                     ((c4 << 3) ^ ((row & 7) << 4))) = pack4bf(sza); }
            { int c = tid + 512; int row = c >> 5, c4 = c & 31;
              *(unsigned long long*)(Lsx + H_OFF + row * 512 +
                                     ((c4 << 3) ^ ((row & 7) << 4))) = pack4bf(szb); }
        }
        if (xv && tid < 32) {
            float s = 0.f;
#pragma unroll
            for (int w = 0; w < 8; ++w) s += *((float*)(lds + RED_OFF) + (w << 5) + tid);
            sOut[((ty - stride) << 5) + tid] = s + cf;
        }
        __syncthreads();
    }
}

// Dense masked pooling: y[b] = sum_a batch[b,a] * s_out[a]
__global__ __launch_bounds__(256) void eqsc_pool(const float* __restrict__ batch,
                                                 const float* __restrict__ s,
                                                 float* __restrict__ out,
                                                 int NA, int B, int CH)
{
    int b  = blockIdx.x % B;
    int ch = blockIdx.x / B;
    int a0 = ch * CH;
    int a1 = min(a0 + CH, NA);
    const float* br = batch + (size_t)b * NA;
    float acc = 0.f;
    for (int a = a0 + (threadIdx.x << 2); a < a1; a += 256 * 4) {
        f32x4 bb = *(const f32x4*)(br + a);
        f32x4 sv = *(const f32x4*)(s + a);
        acc += bb[0] * sv[0] + bb[1] * sv[1] + bb[2] * sv[2] + bb[3] * sv[3];
    }
#pragma unroll
    for (int off = 32; off > 0; off >>= 1) acc += __shfl_down(acc, off);
    __shared__ float wsum[4];
    if ((threadIdx.x & 63) == 0) wsum[threadIdx.x >> 6] = acc;
    __syncthreads();
    if (threadIdx.x == 0) atomicAdd(&out[b], wsum[0] + wsum[1] + wsum[2] + wsum[3]);
}

extern "C" void kernel_launch(void* const* d_in, const int* in_sizes, int n_in,
                              void* d_out, int out_size, void* d_ws, size_t ws_size,
                              hipStream_t stream)
{
    const float* S     = (const float*)d_in[0];
    const float* V     = (const float*)d_in[1];
    // d_in[2] = pos, unused by the reference
    const float* batch = (const float*)d_in[3];
    const float* u0w   = (const float*)d_in[4];
    const float* v0w   = (const float*)d_in[5];
    const float* a0w1  = (const float*)d_in[6];
    const float* a0b1  = (const float*)d_in[7];
    const float* a0w2  = (const float*)d_in[8];
    const float* a0b2  = (const float*)d_in[9];
    const float* u1w   = (const float*)d_in[10];
    const float* v1w   = (const float*)d_in[11];
    const float* a1w1  = (const float*)d_in[12];
    const float* a1b1  = (const float*)d_in[13];
    const float* a1w2  = (const float*)d_in[14];
    const float* a1b2  = (const float*)d_in[15];
    const float* outw  = (const float*)d_in[16];
    const float* outb  = (const float*)d_in[17];

    const int NA = in_sizes[0] / 128;
    const int NT = NA / 32;                  // 32 atoms per tile (200000/32 = 6250)
    const int B  = in_sizes[3] / NA;
    float* sAtom = (float*)d_ws;

    hipMemsetAsync(d_out, 0, (size_t)out_size * sizeof(float), stream);

    eqsc_main<<<256, 512, 0, stream>>>(S, V, u0w, v0w, a0w1, a0b1, a0w2, a0b2,
                                       u1w, v1w, a1w1, a1b1, a1w2, a1b2,
                                       outw, outb, sAtom, NT);

    const int CH  = 16384;
    const int NCH = (NA + CH - 1) / CH;
    eqsc_pool<<<B * NCH, 256, 0, stream>>>(batch, sAtom, (float*)d_out, NA, B, CH);
}

// Round 6
// 448.476 us; speedup vs baseline: 1.0517x; 1.0517x over previous
//
#include <hip/hip_runtime.h>
#include <hip/hip_bf16.h>
#include <math.h>

typedef __attribute__((ext_vector_type(4))) float  f32x4;
typedef __attribute__((ext_vector_type(8))) __bf16 bf16x8;
typedef __attribute__((ext_vector_type(4))) unsigned int u32x4;

__device__ __forceinline__ unsigned short f2bu(float x) {
    __bf16 h = (__bf16)x;
    return __builtin_bit_cast(unsigned short, h);
}

__device__ __forceinline__ f32x4 MF(bf16x8 a, bf16x8 b, f32x4 c) {
    return __builtin_amdgcn_mfma_f32_16x16x32_bf16(a, b, c, 0, 0, 0);
}

__device__ __forceinline__ f32x4 zero4() { f32x4 z = {0.f, 0.f, 0.f, 0.f}; return z; }

// B-fragment (BT row-major, contiguous K): lane holds BT[row][k0..k0+7], f32 -> bf16
__device__ __forceinline__ bf16x8 bfrag_g(const float* W, int ldk, int row, int k0) {
    const float* p = W + (size_t)row * ldk + k0;
    bf16x8 r;
#pragma unroll
    for (int e = 0; e < 8; ++e) r[e] = (__bf16)p[e];
    return r;
}

// ---- LDS layout (bytes), M=32 atoms/tile, two ping-pong bf16 sets + v1 f32 stash ----
// per set: VIN 3*32*256 = 24576 ; H 32*512 = 16384  -> SET_SZ 40960
#define SET_SZ   40960
#define VIN_OFF  0
#define H_OFF    24576
#define S1_OFF   81920   // 32*256 = 8192
#define RED_OFF  90112   // 8 waves * 32 f32 = 1024
#define V1STASH  91136   // v1 f32 stash: 8 waves * 6 * 64 lanes * 16B = 49152
#define LDS_BYTES 140288

// A-fragment read from swizzled LDS tile
__device__ __forceinline__ bf16x8 afrag(const unsigned char* base, int rb, int row, int kb) {
    u32x4 q = *(const u32x4*)(base + row * rb + (kb ^ ((row & 7) << 4)));
    return __builtin_bit_cast(bf16x8, q);
}

__device__ __forceinline__ unsigned long long pack4bf(f32x4 x) {
    return (unsigned long long)f2bu(x[0])
         | ((unsigned long long)f2bu(x[1]) << 16)
         | ((unsigned long long)f2bu(x[2]) << 32)
         | ((unsigned long long)f2bu(x[3]) << 48);
}

// ---- staging helpers (M=32): V tile = 3072 f32x4 (6/thread), S = 1024 (2/thread) ----
__device__ __forceinline__ void load_v(const float* __restrict__ V, int t, int tid, f32x4* vld) {
    const float* vsrc = V + (size_t)t * (32 * 384);
#pragma unroll
    for (int j = 0; j < 6; ++j) vld[j] = *(const f32x4*)(vsrc + ((tid + (j << 9)) << 2));
}
__device__ __forceinline__ void load_s(const float* __restrict__ S, int t, int tid, f32x4* sld) {
    const float* ssrc = S + (size_t)t * (32 * 128);
#pragma unroll
    for (int j = 0; j < 2; ++j) sld[j] = *(const f32x4*)(ssrc + ((tid + (j << 9)) << 2));
}
__device__ __forceinline__ void write_v(unsigned char* dstSet, int tid, const f32x4* vld) {
#pragma unroll
    for (int j = 0; j < 6; ++j) {
        int c = tid + (j << 9);
        int row = c / 96, rem = c - row * 96;
        int d = rem >> 5, c4 = rem & 31;
        *(unsigned long long*)(dstSet + VIN_OFF + (d << 13) + row * 256 +
                               ((c4 << 3) ^ ((row & 7) << 4))) = pack4bf(vld[j]);
    }
}
__device__ __forceinline__ void write_s(unsigned char* dstSet, int tid, const f32x4* sld) {
#pragma unroll
    for (int j = 0; j < 2; ++j) {
        int c = tid + (j << 9);
        int row = c >> 5, c4 = c & 31;
        *(unsigned long long*)(dstSet + H_OFF + row * 512 +
                               ((c4 << 3) ^ ((row & 7) << 4))) = pack4bf(sld[j]);
    }
}

__global__ __launch_bounds__(512, 2) void eqsc_main(
    const float* __restrict__ S, const float* __restrict__ V,
    const float* __restrict__ u0w, const float* __restrict__ v0w,
    const float* __restrict__ a0w1, const float* __restrict__ a0b1,
    const float* __restrict__ a0w2, const float* __restrict__ a0b2,
    const float* __restrict__ u1w, const float* __restrict__ v1w,
    const float* __restrict__ a1w1, const float* __restrict__ a1b1,
    const float* __restrict__ a1w2, const float* __restrict__ a1b2,
    const float* __restrict__ outw, const float* __restrict__ outbp,
    float* __restrict__ sOut, int NT)
{
    __shared__ __align__(16) unsigned char lds[LDS_BYTES];
    const int tid  = threadIdx.x;
    const int lane = tid & 63;
    const int wv   = tid >> 6;
    const int l15  = lane & 15;
    const int lg   = lane >> 4;
    const int grow = wv * 16 + l15;   // this wave/lane's output feature column
    const int kbb  = lg << 4;         // k-byte base within a 64B kt chunk
    unsigned char* const stash = lds + V1STASH + ((wv * 6) << 10) + (lane << 4);

    // ---- folded readout: wfold[k] = sum_g a1w2[g,k]*outw[g]; cfold = b2g1.outw + outb
    float wf = 0.f, cf = 0.f;
    for (int g = 0; g < 128; ++g) {
        float og = outw[g];
        wf += a1w2[g * 128 + grow] * og;
        cf += a1b2[g] * og;
    }
    cf += outbp[0];

    // ---- persistent weight fragments (bf16, MFMA-operand-only -> AGPR-resident) ----
    bf16x8 uw0f[4], vw0f[4], w2g0[4], w2s0[4], vw1f[4];
    bf16x8 w1f0[8], w1f1[8];
#pragma unroll
    for (int kt = 0; kt < 4; ++kt) {
        int k0 = kt * 32 + lg * 8;
        uw0f[kt] = bfrag_g(u0w, 128, grow, k0);
        vw0f[kt] = bfrag_g(v0w, 128, grow, k0);
        w2g0[kt] = bfrag_g(a0w2, 128, grow, k0);
        w2s0[kt] = bfrag_g(a0w2, 128, 128 + grow, k0);
        vw1f[kt] = bfrag_g(v1w, 128, grow, k0);
    }
#pragma unroll
    for (int kt = 0; kt < 8; ++kt) {
        int k0 = kt * 32 + lg * 8;
        w1f0[kt] = bfrag_g(a0w1, 256, grow, k0);
        w1f1[kt] = bfrag_g(a1w1, 256, grow, k0);
    }
    const float b1_0 = a0b1[grow];
    const float b2g0 = a0b2[grow];
    const float b2s0 = a0b2[128 + grow];
    const float b1_1 = a1b1[grow];

    const int stride = gridDim.x;
    const int t0 = blockIdx.x;

    // ---- prologue: reg-stage tile t0 into set 0 ----
    {
        f32x4 vld[6], sld[2];
        load_v(V, t0, tid, vld);
        load_s(S, t0, tid, sld);
        write_v(lds, tid, vld);
        write_s(lds, tid, sld);
    }
    __syncthreads();

    int i = 0;
    for (int ty = t0; ty < NT + stride; ty += stride, ++i) {
        const bool yv = (ty < NT);
        const bool xv = (i > 0);
        const int  tz = ty + stride;
        const bool zv = (tz < NT);
        unsigned char* Lsy = lds + (i & 1) * SET_SZ;
        unsigned char* Lsx = lds + ((i & 1) ^ 1) * SET_SZ;

        // ======== slot 1: Y.P1 (L0 v-phase, v1->stash) || X.P4 (L1 v-phase) ========
        if (yv) {
#pragma unroll
            for (int m = 0; m < 2; ++m) {
                const int mr = m << 4;
                f32x4 n2 = zero4();
#pragma unroll
                for (int d = 0; d < 3; ++d) {
                    f32x4 a1 = zero4(), a2 = zero4();
#pragma unroll
                    for (int kt = 0; kt < 4; ++kt) {
                        bf16x8 a = afrag(Lsy + VIN_OFF + (d << 13), 256, mr + l15, (kt << 6) + kbb);
                        a1 = MF(a, uw0f[kt], a1);
                        a2 = MF(a, vw0f[kt], a2);
                    }
                    *(f32x4*)(stash + (((m * 3 + d)) << 10)) = a1;   // v1 -> LDS stash (f32)
#pragma unroll
                    for (int e = 0; e < 4; ++e) { float x = a2[e] + 1e-8f; n2[e] += x * x; }
                }
#pragma unroll
                for (int e = 0; e < 4; ++e) {
                    int row = mr + (lg << 2) + e;
                    *(unsigned short*)(Lsy + H_OFF + row * 512 +
                        ((256 + (grow << 1)) ^ ((row & 7) << 4))) = f2bu(sqrtf(n2[e]));
                }
            }
        }
        if (xv) {
#pragma unroll
            for (int m = 0; m < 2; ++m) {
                const int mr = m << 4;
                f32x4 n2 = zero4();
#pragma unroll
                for (int d = 0; d < 3; ++d) {
                    f32x4 acc = zero4();
#pragma unroll
                    for (int kt = 0; kt < 4; ++kt)
                        acc = MF(afrag(Lsx + VIN_OFF + (d << 13), 256, mr + l15, (kt << 6) + kbb),
                                 vw1f[kt], acc);
#pragma unroll
                    for (int e = 0; e < 4; ++e) { float x = acc[e] + 1e-8f; n2[e] += x * x; }
                }
#pragma unroll
                for (int e = 0; e < 4; ++e) {
                    int row = mr + (lg << 2) + e;
                    *(unsigned short*)(Lsx + H_OFF + row * 512 +
                        ((256 + (grow << 1)) ^ ((row & 7) << 4))) = f2bu(sqrtf(n2[e]));
                }
            }
        }
        __syncthreads();

        // ======== slot 2: issue V(Z) loads ; Y.P2 || X.P5 ; write V(Z)->Lsx ========
        {
            f32x4 vld[6];
            if (zv) load_v(V, tz, tid, vld);
            if (yv) {
#pragma unroll
                for (int m = 0; m < 2; ++m) {
                    const int mr = m << 4;
                    f32x4 acc = zero4();
#pragma unroll
                    for (int kt = 0; kt < 8; ++kt)
                        acc = MF(afrag(Lsy + H_OFF, 512, mr + l15, (kt << 6) + kbb), w1f0[kt], acc);
#pragma unroll
                    for (int e = 0; e < 4; ++e) {
                        float x = acc[e] + b1_0;
                        float y = x / (1.f + __expf(-x));
                        int row = mr + (lg << 2) + e;
                        *(unsigned short*)(lds + S1_OFF + row * 256 +
                            ((grow << 1) ^ ((row & 7) << 4))) = f2bu(y);
                    }
                }
            }
            if (xv) {
#pragma unroll
                for (int m = 0; m < 2; ++m) {
                    const int mr = m << 4;
                    f32x4 acc = zero4();
#pragma unroll
                    for (int kt = 0; kt < 8; ++kt)
                        acc = MF(afrag(Lsx + H_OFF, 512, mr + l15, (kt << 6) + kbb), w1f1[kt], acc);
                    float p[4];
#pragma unroll
                    for (int e = 0; e < 4; ++e) {
                        float x = acc[e] + b1_1;
                        float y = x / (1.f + __expf(-x));
                        p[e] = y * wf;                 // folded (w2g1^T @ outw) readout, f32
                    }
#pragma unroll
                    for (int off = 1; off < 16; off <<= 1) {
#pragma unroll
                        for (int e = 0; e < 4; ++e) p[e] += __shfl_xor(p[e], off);
                    }
                    if (l15 == 0) {
#pragma unroll
                        for (int e = 0; e < 4; ++e)
                            *((float*)(lds + RED_OFF) + (wv << 5) + mr + (lg << 2) + e) = p[e];
                    }
                }
            }
            if (zv) write_v(Lsx, tid, vld);   // P4-X done with Lsx.VIN since slot-1 barrier
        }
        __syncthreads();

        // ======== slot 3: issue S(Z) loads ; Y.P3 (MLP2 + v'=v1*ss) ; write S(Z) ; sOut(X) ========
        {
            f32x4 sld[2];
            if (zv) load_s(S, tz, tid, sld);
            if (yv) {
#pragma unroll
                for (int m = 0; m < 2; ++m) {
                    const int mr = m << 4;
                    f32x4 sg = zero4(), ssa = zero4();
#pragma unroll
                    for (int kt = 0; kt < 4; ++kt) {
                        bf16x8 a = afrag(lds + S1_OFF, 256, mr + l15, (kt << 6) + kbb);
                        sg  = MF(a, w2g0[kt], sg);
                        ssa = MF(a, w2s0[kt], ssa);
                    }
#pragma unroll
                    for (int e = 0; e < 4; ++e) {
                        int row = mr + (lg << 2) + e;
                        *(unsigned short*)(Lsy + H_OFF + row * 512 +
                            ((grow << 1) ^ ((row & 7) << 4))) = f2bu(sg[e] + b2g0);
                    }
#pragma unroll
                    for (int d = 0; d < 3; ++d) {
                        f32x4 v1 = *(const f32x4*)(stash + ((m * 3 + d) << 10));
#pragma unroll
                        for (int e = 0; e < 4; ++e) {
                            int row = mr + (lg << 2) + e;
                            *(unsigned short*)(Lsy + VIN_OFF + (d << 13) + row * 256 +
                                ((grow << 1) ^ ((row & 7) << 4))) =
                                f2bu(v1[e] * (ssa[e] + b2s0));
                        }
                    }
                }
            }
            if (zv) write_s(Lsx, tid, sld);   // P5-X done with Lsx.H s-half
            if (xv && tid < 32) {
                float s = 0.f;
#pragma unroll
                for (int w = 0; w < 8; ++w) s += *((float*)(lds + RED_OFF) + (w << 5) + tid);
                sOut[((ty - stride) << 5) + tid] = s + cf;
            }
        }
        __syncthreads();
    }
}

// Dense masked pooling: y[b] = sum_a batch[b,a] * s_out[a]
__global__ __launch_bounds__(256) void eqsc_pool(const float* __restrict__ batch,
                                                 const float* __restrict__ s,
                                                 float* __restrict__ out,
                                                 int NA, int B, int CH)
{
    int b  = blockIdx.x % B;
    int ch = blockIdx.x / B;
    int a0 = ch * CH;
    int a1 = min(a0 + CH, NA);
    const float* br = batch + (size_t)b * NA;
    float acc = 0.f;
    for (int a = a0 + (threadIdx.x << 2); a < a1; a += 256 * 4) {
        f32x4 bb = *(const f32x4*)(br + a);
        f32x4 sv = *(const f32x4*)(s + a);
        acc += bb[0] * sv[0] + bb[1] * sv[1] + bb[2] * sv[2] + bb[3] * sv[3];
    }
#pragma unroll
    for (int off = 32; off > 0; off >>= 1) acc += __shfl_down(acc, off);
    __shared__ float wsum[4];
    if ((threadIdx.x & 63) == 0) wsum[threadIdx.x >> 6] = acc;
    __syncthreads();
    if (threadIdx.x == 0) atomicAdd(&out[b], wsum[0] + wsum[1] + wsum[2] + wsum[3]);
}

extern "C" void kernel_launch(void* const* d_in, const int* in_sizes, int n_in,
                              void* d_out, int out_size, void* d_ws, size_t ws_size,
                              hipStream_t stream)
{
    const float* S     = (const float*)d_in[0];
    const float* V     = (const float*)d_in[1];
    // d_in[2] = pos, unused by the reference
    const float* batch = (const float*)d_in[3];
    const float* u0w   = (const float*)d_in[4];
    const float* v0w   = (const float*)d_in[5];
    const float* a0w1  = (const float*)d_in[6];
    const float* a0b1  = (const float*)d_in[7];
    const float* a0w2  = (const float*)d_in[8];
    const float* a0b2  = (const float*)d_in[9];
    const float* u1w   = (const float*)d_in[10];
    const float* v1w   = (const float*)d_in[11];
    const float* a1w1  = (const float*)d_in[12];
    const float* a1b1  = (const float*)d_in[13];
    const float* a1w2  = (const float*)d_in[14];
    const float* a1b2  = (const float*)d_in[15];
    const float* outw  = (const float*)d_in[16];
    const float* outb  = (const float*)d_in[17];

    const int NA = in_sizes[0] / 128;
    const int NT = NA / 32;                  // 32 atoms per tile (200000/32 = 6250)
    const int B  = in_sizes[3] / NA;
    float* sAtom = (float*)d_ws;

    hipMemsetAsync(d_out, 0, (size_t)out_size * sizeof(float), stream);

    eqsc_main<<<256, 512, 0, stream>>>(S, V, u0w, v0w, a0w1, a0b1, a0w2, a0b2,
                                       u1w, v1w, a1w1, a1b1, a1w2, a1b2,
                                       outw, outb, sAtom, NT);

    const int CH  = 16384;
    const int NCH = (NA + CH - 1) / CH;
    eqsc_pool<<<B * NCH, 256, 0, stream>>>(batch, sAtom, (float*)d_out, NA, B, CH);
}

// Round 7
// 384.420 us; speedup vs baseline: 1.2269x; 1.1666x over previous
//
#include <hip/hip_runtime.h>
#include <hip/hip_bf16.h>
#include <math.h>

typedef __attribute__((ext_vector_type(4))) float  f32x4;
typedef __attribute__((ext_vector_type(8))) __bf16 bf16x8;
typedef __attribute__((ext_vector_type(4))) unsigned int u32x4;

__device__ __forceinline__ unsigned short f2bu(float x) {
    __bf16 h = (__bf16)x;
    return __builtin_bit_cast(unsigned short, h);
}

__device__ __forceinline__ f32x4 MF(bf16x8 a, bf16x8 b, f32x4 c) {
    return __builtin_amdgcn_mfma_f32_16x16x32_bf16(a, b, c, 0, 0, 0);
}

__device__ __forceinline__ f32x4 zero4() { f32x4 z = {0.f, 0.f, 0.f, 0.f}; return z; }

// B-fragment (BT row-major, contiguous K): lane holds BT[row][k0..k0+7], f32 -> bf16
__device__ __forceinline__ bf16x8 bfrag_g(const float* W, int ldk, int row, int k0) {
    const float* p = W + (size_t)row * ldk + k0;
    bf16x8 r;
#pragma unroll
    for (int e = 0; e < 8; ++e) r[e] = (__bf16)p[e];
    return r;
}

// ---- LDS layout (bytes), M=16 atoms/tile, THREE rotating bf16 sets + v1 stash x2 ----
// per set: VIN 3*16*256 = 12288 ; H 16*512 = 8192  -> SET_SZ 20480
#define SET_SZ    20480
#define VIN_OFF   0
#define H_OFF     12288
#define S1_OFF    61440   // 16*256 = 4096
#define RED_OFF   65536   // 8 waves * 16 f32 = 512
#define STASH_OFF 66048   // 2 bufs * 8 waves * 3 d * 64 lanes * 16B = 49152
#define STASH_SZ  24576
#define LDS_BYTES 115200

// A-fragment read from swizzled LDS tile
__device__ __forceinline__ bf16x8 afrag(const unsigned char* base, int rb, int row, int kb) {
    u32x4 q = *(const u32x4*)(base + row * rb + (kb ^ ((row & 7) << 4)));
    return __builtin_bit_cast(bf16x8, q);
}

__device__ __forceinline__ unsigned long long pack4bf(f32x4 x) {
    return (unsigned long long)f2bu(x[0])
         | ((unsigned long long)f2bu(x[1]) << 16)
         | ((unsigned long long)f2bu(x[2]) << 32)
         | ((unsigned long long)f2bu(x[3]) << 48);
}

// ---- staging helpers (M=16): V tile = 1536 f32x4 (3/thread), S = 512 (1/thread) ----
__device__ __forceinline__ void load_v(const float* __restrict__ V, int t, int tid, f32x4* vld) {
    const float* vsrc = V + (size_t)t * (16 * 384);
#pragma unroll
    for (int j = 0; j < 3; ++j) vld[j] = *(const f32x4*)(vsrc + ((tid + (j << 9)) << 2));
}
__device__ __forceinline__ void write_v(unsigned char* dstSet, int tid, const f32x4* vld) {
#pragma unroll
    for (int j = 0; j < 3; ++j) {
        int c = tid + (j << 9);
        int row = c / 96, rem = c - row * 96;
        int d = rem >> 5, c4 = rem & 31;
        *(unsigned long long*)(dstSet + VIN_OFF + (d << 12) + row * 256 +
                               ((c4 << 3) ^ ((row & 7) << 4))) = pack4bf(vld[j]);
    }
}

__global__ __launch_bounds__(512, 2) void eqsc_main(
    const float* __restrict__ S, const float* __restrict__ V,
    const float* __restrict__ u0w, const float* __restrict__ v0w,
    const float* __restrict__ a0w1, const float* __restrict__ a0b1,
    const float* __restrict__ a0w2, const float* __restrict__ a0b2,
    const float* __restrict__ u1w, const float* __restrict__ v1w,
    const float* __restrict__ a1w1, const float* __restrict__ a1b1,
    const float* __restrict__ a1w2, const float* __restrict__ a1b2,
    const float* __restrict__ outw, const float* __restrict__ outbp,
    float* __restrict__ sOut, int NT)
{
    __shared__ __align__(16) unsigned char lds[LDS_BYTES];
    const int tid  = threadIdx.x;
    const int lane = tid & 63;
    const int wvv  = tid >> 6;
    const int l15  = lane & 15;
    const int lg   = lane >> 4;
    const int grow = wvv * 16 + l15;  // this wave/lane's output feature column
    const int kbb  = lg << 4;         // k-byte base within a 64B kt chunk

    // ---- folded readout: wfold[k] = sum_g a1w2[g,k]*outw[g]; cfold = b2g1.outw + outb
    float wf = 0.f, cf = 0.f;
    for (int g = 0; g < 128; ++g) {
        float og = outw[g];
        wf += a1w2[g * 128 + grow] * og;
        cf += a1b2[g] * og;
    }
    cf += outbp[0];

    // ---- persistent weight fragments (bf16, MFMA-operand-only) ----
    bf16x8 uw0f[4], vw0f[4], w2g0[4], w2s0[4], vw1f[4];
    bf16x8 w1f0[8], w1f1[8];
#pragma unroll
    for (int kt = 0; kt < 4; ++kt) {
        int k0 = kt * 32 + lg * 8;
        uw0f[kt] = bfrag_g(u0w, 128, grow, k0);
        vw0f[kt] = bfrag_g(v0w, 128, grow, k0);
        w2g0[kt] = bfrag_g(a0w2, 128, grow, k0);
        w2s0[kt] = bfrag_g(a0w2, 128, 128 + grow, k0);
        vw1f[kt] = bfrag_g(v1w, 128, grow, k0);
    }
#pragma unroll
    for (int kt = 0; kt < 8; ++kt) {
        int k0 = kt * 32 + lg * 8;
        w1f0[kt] = bfrag_g(a0w1, 256, grow, k0);
        w1f1[kt] = bfrag_g(a1w1, 256, grow, k0);
    }
    const float b1_0 = a0b1[grow];
    const float b2g0 = a0b2[grow];
    const float b2s0 = a0b2[128 + grow];
    const float b1_1 = a1b1[grow];

    const int stride = gridDim.x;
    const int t0 = blockIdx.x;
    const int NI = (NT - t0 + stride - 1) / stride;   // tiles this block owns

    // ---- prologue: stage V(T0) into set 0 ----
    {
        f32x4 vld[3];
        load_v(V, t0, tid, vld);
        write_v(lds, tid, vld);
    }
    __syncthreads();

    for (int i = 0; i < NI + 3; ++i) {
        const int ty = t0 + i * stride;
        const bool yv = (i < NI);
        const bool xvd = (i >= 1) && (i - 1 < NI);
        const bool wvd = (i >= 2) && (i - 2 < NI);
        const bool fvd = (i >= 3) && (i - 3 < NI);
        const bool zvd = (i + 1 < NI);
        unsigned char* setY = lds + (i % 3) * SET_SZ;
        unsigned char* setX = lds + ((i + 2) % 3) * SET_SZ;
        unsigned char* setW = lds + ((i + 1) % 3) * SET_SZ;
        unsigned char* stashY = lds + STASH_OFF + (i & 1) * STASH_SZ + wvv * 3072 + (lane << 4);
        unsigned char* stashX = lds + STASH_OFF + ((i & 1) ^ 1) * STASH_SZ + wvv * 3072 + (lane << 4);

        // ======== slot 1: flush(F) ; P1(Y) v-phase L0 ; P3(X) MLP2 L0 ; stage S(Y) ========
        if (fvd && tid < 16) {                           // RED written at s2(i-1)
            float s = 0.f;
#pragma unroll
            for (int w = 0; w < 8; ++w) s += *((float*)(lds + RED_OFF) + (w << 4) + tid);
            sOut[((t0 + (i - 3) * stride) << 4) + tid] = s + cf;
        }
        f32x4 sldY;
        if (yv) sldY = *(const f32x4*)(S + (size_t)ty * (16 * 128) + (tid << 2));

        if (yv) {                                        // P1: v1->stash, v2->norm
            f32x4 n2 = zero4();
#pragma unroll
            for (int d = 0; d < 3; ++d) {
                f32x4 a1 = zero4(), a2 = zero4();
#pragma unroll
                for (int kt = 0; kt < 4; ++kt) {
                    bf16x8 a = afrag(setY + VIN_OFF + (d << 12), 256, l15, (kt << 6) + kbb);
                    a1 = MF(a, uw0f[kt], a1);
                    a2 = MF(a, vw0f[kt], a2);
                }
                *(f32x4*)(stashY + (d << 10)) = a1;      // conflict-free lane-linear b128
#pragma unroll
                for (int e = 0; e < 4; ++e) { float x = a2[e] + 1e-8f; n2[e] += x * x; }
            }
#pragma unroll
            for (int e = 0; e < 4; ++e) {
                int row = (lg << 2) + e;
                *(unsigned short*)(setY + H_OFF + row * 512 +
                    ((256 + (grow << 1)) ^ ((row & 7) << 4))) = f2bu(sqrtf(n2[e]));
            }
        }
        if (xvd) {                                       // P3: sg|ss ; v' = v1*ss
            f32x4 sg = zero4(), ssa = zero4();
#pragma unroll
            for (int kt = 0; kt < 4; ++kt) {
                bf16x8 a = afrag(lds + S1_OFF, 256, l15, (kt << 6) + kbb);
                sg  = MF(a, w2g0[kt], sg);
                ssa = MF(a, w2s0[kt], ssa);
            }
#pragma unroll
            for (int e = 0; e < 4; ++e) {
                int row = (lg << 2) + e;
                *(unsigned short*)(setX + H_OFF + row * 512 +
                    ((grow << 1) ^ ((row & 7) << 4))) = f2bu(sg[e] + b2g0);
            }
#pragma unroll
            for (int d = 0; d < 3; ++d) {
                f32x4 v1 = *(const f32x4*)(stashX + (d << 10));
#pragma unroll
                for (int e = 0; e < 4; ++e) {
                    int row = (lg << 2) + e;
                    *(unsigned short*)(setX + VIN_OFF + (d << 12) + row * 256 +
                        ((grow << 1) ^ ((row & 7) << 4))) = f2bu(v1[e] * (ssa[e] + b2s0));
                }
            }
        }
        if (yv) {                                        // S(Y) -> setY H s-part
            int row = tid >> 5, c4 = tid & 31;
            *(unsigned long long*)(setY + H_OFF + row * 512 +
                                   ((c4 << 3) ^ ((row & 7) << 4))) = pack4bf(sldY);
        }
        __syncthreads();

        // ======== slot 2: P2(Y) MLP1-L0 ; P4(X) v-phase L1 ; P5(W) MLP1-L1+readout ; stage V(Z) ========
        f32x4 vldZ[3];
        if (zvd) load_v(V, ty + stride, tid, vldZ);

        if (yv) {                                        // P2
            f32x4 acc = zero4();
#pragma unroll
            for (int kt = 0; kt < 8; ++kt)
                acc = MF(afrag(setY + H_OFF, 512, l15, (kt << 6) + kbb), w1f0[kt], acc);
#pragma unroll
            for (int e = 0; e < 4; ++e) {
                float x = acc[e] + b1_0;
                float y = x / (1.f + __expf(-x));
                int row = (lg << 2) + e;
                *(unsigned short*)(lds + S1_OFF + row * 256 +
                    ((grow << 1) ^ ((row & 7) << 4))) = f2bu(y);
            }
        }
        if (xvd) {                                       // P4 (L1 v1 is dead code)
            f32x4 n2 = zero4();
#pragma unroll
            for (int d = 0; d < 3; ++d) {
                f32x4 acc = zero4();
#pragma unroll
                for (int kt = 0; kt < 4; ++kt)
                    acc = MF(afrag(setX + VIN_OFF + (d << 12), 256, l15, (kt << 6) + kbb),
                             vw1f[kt], acc);
#pragma unroll
                for (int e = 0; e < 4; ++e) { float x = acc[e] + 1e-8f; n2[e] += x * x; }
            }
#pragma unroll
            for (int e = 0; e < 4; ++e) {
                int row = (lg << 2) + e;
                *(unsigned short*)(setX + H_OFF + row * 512 +
                    ((256 + (grow << 1)) ^ ((row & 7) << 4))) = f2bu(sqrtf(n2[e]));
            }
        }
        if (wvd) {                                       // P5 + folded readout
            f32x4 acc = zero4();
#pragma unroll
            for (int kt = 0; kt < 8; ++kt)
                acc = MF(afrag(setW + H_OFF, 512, l15, (kt << 6) + kbb), w1f1[kt], acc);
            float p[4];
#pragma unroll
            for (int e = 0; e < 4; ++e) {
                float x = acc[e] + b1_1;
                float y = x / (1.f + __expf(-x));
                p[e] = y * wf;                           // folded (w2g1^T @ outw), f32
            }
#pragma unroll
            for (int off = 1; off < 16; off <<= 1) {
#pragma unroll
                for (int e = 0; e < 4; ++e) p[e] += __shfl_xor(p[e], off);
            }
            if (l15 == 0) {
#pragma unroll
                for (int e = 0; e < 4; ++e)
                    *((float*)(lds + RED_OFF) + (wvv << 4) + (lg << 2) + e) = p[e];
            }
        }
        if (zvd) write_v(setW, tid, vldZ);               // VIN region of setW: dead (disjoint from H'_W reads)
        __syncthreads();
    }
}

// Dense masked pooling: y[b] = sum_a batch[b,a] * s_out[a]
__global__ __launch_bounds__(256) void eqsc_pool(const float* __restrict__ batch,
                                                 const float* __restrict__ s,
                                                 float* __restrict__ out,
                                                 int NA, int B, int CH)
{
    int b  = blockIdx.x % B;
    int ch = blockIdx.x / B;
    int a0 = ch * CH;
    int a1 = min(a0 + CH, NA);
    const float* br = batch + (size_t)b * NA;
    float acc = 0.f;
    for (int a = a0 + (threadIdx.x << 2); a < a1; a += 256 * 4) {
        f32x4 bb = *(const f32x4*)(br + a);
        f32x4 sv = *(const f32x4*)(s + a);
        acc += bb[0] * sv[0] + bb[1] * sv[1] + bb[2] * sv[2] + bb[3] * sv[3];
    }
#pragma unroll
    for (int off = 32; off > 0; off >>= 1) acc += __shfl_down(acc, off);
    __shared__ float wsum[4];
    if ((threadIdx.x & 63) == 0) wsum[threadIdx.x >> 6] = acc;
    __syncthreads();
    if (threadIdx.x == 0) atomicAdd(&out[b], wsum[0] + wsum[1] + wsum[2] + wsum[3]);
}

extern "C" void kernel_launch(void* const* d_in, const int* in_sizes, int n_in,
                              void* d_out, int out_size, void* d_ws, size_t ws_size,
                              hipStream_t stream)
{
    const float* S     = (const float*)d_in[0];
    const float* V     = (const float*)d_in[1];
    // d_in[2] = pos, unused by the reference
    const float* batch = (const float*)d_in[3];
    const float* u0w   = (const float*)d_in[4];
    const float* v0w   = (const float*)d_in[5];
    const float* a0w1  = (const float*)d_in[6];
    const float* a0b1  = (const float*)d_in[7];
    const float* a0w2  = (const float*)d_in[8];
    const float* a0b2  = (const float*)d_in[9];
    const float* u1w   = (const float*)d_in[10];
    const float* v1w   = (const float*)d_in[11];
    const float* a1w1  = (const float*)d_in[12];
    const float* a1b1  = (const float*)d_in[13];
    const float* a1w2  = (const float*)d_in[14];
    const float* a1b2  = (const float*)d_in[15];
    const float* outw  = (const float*)d_in[16];
    const float* outb  = (const float*)d_in[17];

    const int NA = in_sizes[0] / 128;
    const int NT = NA / 16;                  // 16 atoms per tile
    const int B  = in_sizes[3] / NA;
    float* sAtom = (float*)d_ws;

    hipMemsetAsync(d_out, 0, (size_t)out_size * sizeof(float), stream);

    eqsc_main<<<256, 512, 0, stream>>>(S, V, u0w, v0w, a0w1, a0b1, a0w2, a0b2,
                                       u1w, v1w, a1w1, a1b1, a1w2, a1b2,
                                       outw, outb, sAtom, NT);

    const int CH  = 16384;
    const int NCH = (NA + CH - 1) / CH;
    eqsc_pool<<<B * NCH, 256, 0, stream>>>(batch, sAtom, (float*)d_out, NA, B, CH);
}

// Round 8
// 360.989 us; speedup vs baseline: 1.3066x; 1.0649x over previous
//
#include <hip/hip_runtime.h>
#include <hip/hip_bf16.h>
#include <math.h>

typedef __attribute__((ext_vector_type(4))) float  f32x4;
typedef __attribute__((ext_vector_type(8))) __bf16 bf16x8;
typedef __attribute__((ext_vector_type(4))) unsigned int u32x4;

__device__ __forceinline__ unsigned short f2bu(float x) {
    __bf16 h = (__bf16)x;
    return __builtin_bit_cast(unsigned short, h);
}

__device__ __forceinline__ f32x4 MF(bf16x8 a, bf16x8 b, f32x4 c) {
    return __builtin_amdgcn_mfma_f32_16x16x32_bf16(a, b, c, 0, 0, 0);
}

__device__ __forceinline__ f32x4 zero4() { f32x4 z = {0.f, 0.f, 0.f, 0.f}; return z; }

// B-fragment (BT row-major, contiguous K): lane holds BT[row][k0..k0+7], f32 -> bf16
__device__ __forceinline__ bf16x8 bfrag_g(const float* W, int ldk, int row, int k0) {
    const float* p = W + (size_t)row * ldk + k0;
    bf16x8 r;
#pragma unroll
    for (int e = 0; e < 8; ++e) r[e] = (__bf16)p[e];
    return r;
}

// ---- LDS layout (bytes), M=16 atoms/tile ----
// VINraw bank: [3][16][256B] = 12288 ; v' bank: same ; H0/H': [16][512B] = 8192
#define VRAW(b)  ((b) * 12288)             // raw V tiles, ping-pong
#define VPRM(b)  (24576 + (b) * 12288)     // v' = v1*ss tiles, ping-pong
#define H0_OFF   49152                     // L0 MLP1 input [s | norm]
#define HP(b)    (57344 + (b) * 8192)      // L1 MLP1 input, 3 rotating banks
#define S1_OFF   81920                     // L0 MLP1 output (16x128 bf16)
#define RED_OFF  86016                     // 8 waves * 16 f32
#define LDS_BYTES 86528

// A-fragment read from swizzled LDS tile
__device__ __forceinline__ bf16x8 afrag(const unsigned char* base, int rb, int row, int kb) {
    u32x4 q = *(const u32x4*)(base + row * rb + (kb ^ ((row & 7) << 4)));
    return __builtin_bit_cast(bf16x8, q);
}

__device__ __forceinline__ unsigned long long pack4bf(f32x4 x) {
    return (unsigned long long)f2bu(x[0])
         | ((unsigned long long)f2bu(x[1]) << 16)
         | ((unsigned long long)f2bu(x[2]) << 32)
         | ((unsigned long long)f2bu(x[3]) << 48);
}

// ---- staging helpers (M=16): V tile = 1536 f32x4 (3/thread), S = 512 (1/thread) ----
__device__ __forceinline__ void load_v(const float* __restrict__ V, int t, int tid, f32x4* vld) {
    const float* vsrc = V + (size_t)t * (16 * 384);
#pragma unroll
    for (int j = 0; j < 3; ++j) vld[j] = *(const f32x4*)(vsrc + ((tid + (j << 9)) << 2));
}
__device__ __forceinline__ void write_v(unsigned char* dstBank, int tid, const f32x4* vld) {
#pragma unroll
    for (int j = 0; j < 3; ++j) {
        int c = tid + (j << 9);
        int row = c / 96, rem = c - row * 96;
        int d = rem >> 5, c4 = rem & 31;
        *(unsigned long long*)(dstBank + (d << 12) + row * 256 +
                               ((c4 << 3) ^ ((row & 7) << 4))) = pack4bf(vld[j]);
    }
}

__global__ __launch_bounds__(512, 2) void eqsc_main(
    const float* __restrict__ S, const float* __restrict__ V,
    const float* __restrict__ u0w, const float* __restrict__ v0w,
    const float* __restrict__ a0w1, const float* __restrict__ a0b1,
    const float* __restrict__ a0w2, const float* __restrict__ a0b2,
    const float* __restrict__ u1w, const float* __restrict__ v1w,
    const float* __restrict__ a1w1, const float* __restrict__ a1b1,
    const float* __restrict__ a1w2, const float* __restrict__ a1b2,
    const float* __restrict__ outw, const float* __restrict__ outbp,
    float* __restrict__ sOut, int NT)
{
    __shared__ __align__(16) unsigned char lds[LDS_BYTES];
    const int tid  = threadIdx.x;
    const int lane = tid & 63;
    const int wvv  = tid >> 6;
    const int l15  = lane & 15;
    const int lg   = lane >> 4;
    const int grow = wvv * 16 + l15;  // this wave/lane's output feature column
    const int kbb  = lg << 4;         // k-byte base within a 64B kt chunk

    // ---- folded readout: wfold[k] = sum_g a1w2[g,k]*outw[g]; cfold = b2g1.outw + outb
    float wf = 0.f, cf = 0.f;
    for (int g = 0; g < 128; ++g) {
        float og = outw[g];
        wf += a1w2[g * 128 + grow] * og;
        cf += a1b2[g] * og;
    }
    cf += outbp[0];

    // ---- persistent weight fragments (bf16, MFMA-operand-only): 144 regs ----
    bf16x8 uw0f[4], vw0f[4], w2g0[4], w2s0[4], vw1f[4];
    bf16x8 w1f0[8], w1f1[8];
#pragma unroll
    for (int kt = 0; kt < 4; ++kt) {
        int k0 = kt * 32 + lg * 8;
        uw0f[kt] = bfrag_g(u0w, 128, grow, k0);
        vw0f[kt] = bfrag_g(v0w, 128, grow, k0);
        w2g0[kt] = bfrag_g(a0w2, 128, grow, k0);
        w2s0[kt] = bfrag_g(a0w2, 128, 128 + grow, k0);
        vw1f[kt] = bfrag_g(v1w, 128, grow, k0);
    }
#pragma unroll
    for (int kt = 0; kt < 8; ++kt) {
        int k0 = kt * 32 + lg * 8;
        w1f0[kt] = bfrag_g(a0w1, 256, grow, k0);
        w1f1[kt] = bfrag_g(a1w1, 256, grow, k0);
    }
    const float b1_0 = a0b1[grow];
    const float b2g0 = a0b2[grow];
    const float b2s0 = a0b2[128 + grow];
    const float b1_1 = a1b1[grow];

    const int stride = gridDim.x;
    const int t0 = blockIdx.x;
    const int NI = (NT > t0) ? ((NT - t0 + stride - 1) / stride) : 0;

    // ---- prologue: stage V(t0) into VINraw bank 0 ----
    if (NI > 0) {
        f32x4 vld[3];
        load_v(V, t0, tid, vld);
        write_v(lds + VRAW(0), tid, vld);
    }
    __syncthreads();

    for (int i = 0; i < NI + 2; ++i) {
        const bool v1v = (i < NI);                 // tile Y = i
        const bool v2v = (i >= 1) && (i - 1 < NI); // tile X = i-1
        const bool v3v = (i >= 2) && (i - 2 < NI); // tile W = i-2
        const bool zv  = (i + 1 < NI);
        const int hY = i % 3, hX = (i + 2) % 3, hW = (i + 1) % 3;
        const int rY = i & 1;                      // VINraw bank of Y
        const int pX = (i + 1) & 1, pY = i & 1;    // v' banks
        const int ty = t0 + i * stride;

        // ======== slot 1: P1(Y) v-GEMM+norm ; P5(W) MLP1-L1+readout ; stage S(Y) ========
        f32x4 sldY;
        if (v1v) sldY = *(const f32x4*)(S + (size_t)ty * 2048 + (tid << 2));
        if (v1v) {                                  // P1: v2 = V@v0w^T, norm over d
            f32x4 n2 = zero4();
#pragma unroll
            for (int d = 0; d < 3; ++d) {
                f32x4 a2 = zero4();
#pragma unroll
                for (int kt = 0; kt < 4; ++kt)
                    a2 = MF(afrag(lds + VRAW(rY) + (d << 12), 256, l15, (kt << 6) + kbb),
                            vw0f[kt], a2);
#pragma unroll
                for (int e = 0; e < 4; ++e) { float x = a2[e] + 1e-8f; n2[e] += x * x; }
            }
#pragma unroll
            for (int e = 0; e < 4; ++e) {
                int row = (lg << 2) + e;
                *(unsigned short*)(lds + H0_OFF + row * 512 +
                    ((256 + (grow << 1)) ^ ((row & 7) << 4))) = f2bu(sqrtf(n2[e]));
            }
        }
        if (v3v) {                                  // P5: MLP1-L1 + folded readout
            f32x4 acc = zero4();
#pragma unroll
            for (int kt = 0; kt < 8; ++kt)
                acc = MF(afrag(lds + HP(hW), 512, l15, (kt << 6) + kbb), w1f1[kt], acc);
            float p[4];
#pragma unroll
            for (int e = 0; e < 4; ++e) {
                float x = acc[e] + b1_1;
                float y = x / (1.f + __expf(-x));
                p[e] = y * wf;                      // folded (w2g1^T @ outw), f32
            }
#pragma unroll
            for (int off = 1; off < 16; off <<= 1) {
#pragma unroll
                for (int e = 0; e < 4; ++e) p[e] += __shfl_xor(p[e], off);
            }
            if (l15 == 0) {
#pragma unroll
                for (int e = 0; e < 4; ++e)
                    *((float*)(lds + RED_OFF) + (wvv << 4) + (lg << 2) + e) = p[e];
            }
        }
        if (v1v) {                                  // S(Y) -> H0 s-half
            int row = tid >> 5, c4 = tid & 31;
            *(unsigned long long*)(lds + H0_OFF + row * 512 +
                                   ((c4 << 3) ^ ((row & 7) << 4))) = pack4bf(sldY);
        }
        __syncthreads();

        // ======== slot 2: P2(Y) MLP1-L0 ; P4(X) L1 v-phase ; flush sOut(W) ; load V(Z) ========
        f32x4 vldZ[3];
        if (zv) load_v(V, ty + stride, tid, vldZ);
        if (v1v) {                                  // P2
            f32x4 acc = zero4();
#pragma unroll
            for (int kt = 0; kt < 8; ++kt)
                acc = MF(afrag(lds + H0_OFF, 512, l15, (kt << 6) + kbb), w1f0[kt], acc);
#pragma unroll
            for (int e = 0; e < 4; ++e) {
                float x = acc[e] + b1_0;
                float y = x / (1.f + __expf(-x));
                int row = (lg << 2) + e;
                *(unsigned short*)(lds + S1_OFF + row * 256 +
                    ((grow << 1) ^ ((row & 7) << 4))) = f2bu(y);
            }
        }
        if (v2v) {                                  // P4: v2' = v'@v1w^T, norm
            f32x4 n2 = zero4();
#pragma unroll
            for (int d = 0; d < 3; ++d) {
                f32x4 acc = zero4();
#pragma unroll
                for (int kt = 0; kt < 4; ++kt)
                    acc = MF(afrag(lds + VPRM(pX) + (d << 12), 256, l15, (kt << 6) + kbb),
                             vw1f[kt], acc);
#pragma unroll
                for (int e = 0; e < 4; ++e) { float x = acc[e] + 1e-8f; n2[e] += x * x; }
            }
#pragma unroll
            for (int e = 0; e < 4; ++e) {
                int row = (lg << 2) + e;
                *(unsigned short*)(lds + HP(hX) + row * 512 +
                    ((256 + (grow << 1)) ^ ((row & 7) << 4))) = f2bu(sqrtf(n2[e]));
            }
        }
        if (v3v && tid < 16) {                      // flush tile W (RED written slot 1)
            float s = 0.f;
#pragma unroll
            for (int w = 0; w < 8; ++w) s += *((float*)(lds + RED_OFF) + (w << 4) + tid);
            sOut[((t0 + (i - 2) * stride) << 4) + tid] = s + cf;
        }
        __syncthreads();

        // ======== slot 3: P3(Y) sg/ss + deferred u-GEMM -> gate,v' ; write V(Z) ========
        if (v1v) {
            f32x4 sg = zero4(), ssa = zero4();
#pragma unroll
            for (int kt = 0; kt < 4; ++kt) {
                bf16x8 a = afrag(lds + S1_OFF, 256, l15, (kt << 6) + kbb);
                sg  = MF(a, w2g0[kt], sg);
                ssa = MF(a, w2s0[kt], ssa);
            }
            f32x4 v1acc[3];
#pragma unroll
            for (int d = 0; d < 3; ++d) {
                f32x4 acc = zero4();
#pragma unroll
                for (int kt = 0; kt < 4; ++kt)
                    acc = MF(afrag(lds + VRAW(rY) + (d << 12), 256, l15, (kt << 6) + kbb),
                             uw0f[kt], acc);
                v1acc[d] = acc;
            }
#pragma unroll
            for (int e = 0; e < 4; ++e) {
                int row = (lg << 2) + e;
                int swz = (row & 7) << 4;
                *(unsigned short*)(lds + HP(hY) + row * 512 + ((grow << 1) ^ swz)) =
                    f2bu(sg[e] + b2g0);
                float ssv = ssa[e] + b2s0;
#pragma unroll
                for (int d = 0; d < 3; ++d)
                    *(unsigned short*)(lds + VPRM(pY) + (d << 12) + row * 256 +
                        ((grow << 1) ^ swz)) = f2bu(v1acc[d][e] * ssv);
            }
        }
        if (zv) write_v(lds + VRAW((i + 1) & 1), tid, vldZ);
        __syncthreads();
    }
}

// Dense masked pooling: y[b] = sum_a batch[b,a] * s_out[a]
__global__ __launch_bounds__(256) void eqsc_pool(const float* __restrict__ batch,
                                                 const float* __restrict__ s,
                                                 float* __restrict__ out,
                                                 int NA, int B, int CH)
{
    int b  = blockIdx.x % B;
    int ch = blockIdx.x / B;
    int a0 = ch * CH;
    int a1 = min(a0 + CH, NA);
    const float* br = batch + (size_t)b * NA;
    float acc = 0.f;
    for (int a = a0 + (threadIdx.x << 2); a < a1; a += 256 * 4) {
        f32x4 bb = *(const f32x4*)(br + a);
        f32x4 sv = *(const f32x4*)(s + a);
        acc += bb[0] * sv[0] + bb[1] * sv[1] + bb[2] * sv[2] + bb[3] * sv[3];
    }
#pragma unroll
    for (int off = 32; off > 0; off >>= 1) acc += __shfl_down(acc, off);
    __shared__ float wsum[4];
    if ((threadIdx.x & 63) == 0) wsum[threadIdx.x >> 6] = acc;
    __syncthreads();
    if (threadIdx.x == 0) atomicAdd(&out[b], wsum[0] + wsum[1] + wsum[2] + wsum[3]);
}

extern "C" void kernel_launch(void* const* d_in, const int* in_sizes, int n_in,
                              void* d_out, int out_size, void* d_ws, size_t ws_size,
                              hipStream_t stream)
{
    const float* S     = (const float*)d_in[0];
    const float* V     = (const float*)d_in[1];
    // d_in[2] = pos, unused by the reference
    const float* batch = (const float*)d_in[3];
    const float* u0w   = (const float*)d_in[4];
    const float* v0w   = (const float*)d_in[5];
    const float* a0w1  = (const float*)d_in[6];
    const float* a0b1  = (const float*)d_in[7];
    const float* a0w2  = (const float*)d_in[8];
    const float* a0b2  = (const float*)d_in[9];
    const float* u1w   = (const float*)d_in[10];
    const float* v1w   = (const float*)d_in[11];
    const float* a1w1  = (const float*)d_in[12];
    const float* a1b1  = (const float*)d_in[13];
    const float* a1w2  = (const float*)d_in[14];
    const float* a1b2  = (const float*)d_in[15];
    const float* outw  = (const float*)d_in[16];
    const float* outb  = (const float*)d_in[17];

    const int NA = in_sizes[0] / 128;
    const int NT = NA / 16;                  // 16 atoms per tile
    const int B  = in_sizes[3] / NA;
    float* sAtom = (float*)d_ws;

    hipMemsetAsync(d_out, 0, (size_t)out_size * sizeof(float), stream);

    eqsc_main<<<256, 512, 0, stream>>>(S, V, u0w, v0w, a0w1, a0b1, a0w2, a0b2,
                                       u1w, v1w, a1w1, a1b1, a1w2, a1b2,
                                       outw, outb, sAtom, NT);

    const int CH  = 16384;
    const int NCH = (NA + CH - 1) / CH;
    eqsc_pool<<<B * NCH, 256, 0, stream>>>(batch, sAtom, (float*)d_out, NA, B, CH);
}

// Round 9
// 329.130 us; speedup vs baseline: 1.4331x; 1.0968x over previous
//
#include <hip/hip_runtime.h>
#include <hip/hip_bf16.h>
#include <math.h>

typedef __attribute__((ext_vector_type(4))) float  f32x4;
typedef __attribute__((ext_vector_type(8))) __bf16 bf16x8;
typedef __attribute__((ext_vector_type(4))) unsigned int u32x4;

__device__ __forceinline__ unsigned short f2bu(float x) {
    __bf16 h = (__bf16)x;
    return __builtin_bit_cast(unsigned short, h);
}

__device__ __forceinline__ f32x4 MF(bf16x8 a, bf16x8 b, f32x4 c) {
    return __builtin_amdgcn_mfma_f32_16x16x32_bf16(a, b, c, 0, 0, 0);
}

__device__ __forceinline__ f32x4 zero4() { f32x4 z = {0.f, 0.f, 0.f, 0.f}; return z; }

// B-fragment (BT row-major, contiguous K): lane holds BT[row][k0..k0+7], f32 -> bf16
__device__ __forceinline__ bf16x8 bfrag_g(const float* W, int ldk, int row, int k0) {
    const float* p = W + (size_t)row * ldk + k0;
    bf16x8 r;
#pragma unroll
    for (int e = 0; e < 8; ++e) r[e] = (__bf16)p[e];
    return r;
}

// ---- LDS layout (bytes), M=16 atoms/tile, two ping-pong sets ----
// per set: VIN 3*16*256 = 12288 ; H 16*512 = 8192  -> SET_SZ 20480
#define SET_SZ   20480
#define VIN_OFF  0
#define H_OFF    12288
#define S1_OFF   40960   // single shared S1: 16*256 = 4096
#define RED_OFF  45056   // 8 waves * 16 f32 = 512
#define LDS_BYTES 45568

// A-fragment read from swizzled LDS tile
__device__ __forceinline__ bf16x8 afrag(const unsigned char* base, int rb, int row, int kb) {
    u32x4 q = *(const u32x4*)(base + row * rb + (kb ^ ((row & 7) << 4)));
    return __builtin_bit_cast(bf16x8, q);
}

__device__ __forceinline__ unsigned long long pack4bf(f32x4 x) {
    return (unsigned long long)f2bu(x[0])
         | ((unsigned long long)f2bu(x[1]) << 16)
         | ((unsigned long long)f2bu(x[2]) << 32)
         | ((unsigned long long)f2bu(x[3]) << 48);
}

__global__ __launch_bounds__(512, 2) void eqsc_main(
    const float* __restrict__ S, const float* __restrict__ V,
    const float* __restrict__ u0w, const float* __restrict__ v0w,
    const float* __restrict__ a0w1, const float* __restrict__ a0b1,
    const float* __restrict__ a0w2, const float* __restrict__ a0b2,
    const float* __restrict__ u1w, const float* __restrict__ v1w,
    const float* __restrict__ a1w1, const float* __restrict__ a1b1,
    const float* __restrict__ a1w2, const float* __restrict__ a1b2,
    const float* __restrict__ outw, const float* __restrict__ outbp,
    float* __restrict__ sOut, int NT)
{
    __shared__ __align__(16) unsigned char lds[LDS_BYTES];
    const int tid  = threadIdx.x;
    const int lane = tid & 63;
    const int wv   = tid >> 6;
    const int l15  = lane & 15;
    const int lg   = lane >> 4;
    const int grow = wv * 16 + l15;   // this wave/lane's output feature column
    const int kbb  = lg << 4;         // k-byte base within a 64B kt chunk

    // ---- folded readout: wfold[k] = sum_g a1w2[g,k]*outw[g]; cfold = b2g1.outw + outb
    float wf = 0.f, cf = 0.f;
    for (int g = 0; g < 128; ++g) {
        float og = outw[g];
        wf += a1w2[g * 128 + grow] * og;
        cf += a1b2[g] * og;
    }
    cf += outbp[0];

    // ---- persistent weight fragments (bf16, register-resident): 144 regs ----
    bf16x8 uw0f[4], vw0f[4], w2g0[4], w2s0[4], vw1f[4];
    bf16x8 w1f0[8], w1f1[8];
#pragma unroll
    for (int kt = 0; kt < 4; ++kt) {
        int k0 = kt * 32 + lg * 8;
        uw0f[kt] = bfrag_g(u0w, 128, grow, k0);
        vw0f[kt] = bfrag_g(v0w, 128, grow, k0);
        w2g0[kt] = bfrag_g(a0w2, 128, grow, k0);
        w2s0[kt] = bfrag_g(a0w2, 128, 128 + grow, k0);
        vw1f[kt] = bfrag_g(v1w, 128, grow, k0);
    }
#pragma unroll
    for (int kt = 0; kt < 8; ++kt) {
        int k0 = kt * 32 + lg * 8;
        w1f0[kt] = bfrag_g(a0w1, 256, grow, k0);
        w1f1[kt] = bfrag_g(a1w1, 256, grow, k0);
    }
    const float b1_0 = a0b1[grow];
    const float b2g0 = a0b2[grow];
    const float b2s0 = a0b2[128 + grow];
    const float b1_1 = a1b1[grow];

    const int stride = gridDim.x;
    const int t0 = blockIdx.x;

    // ---- prologue: stage tile t0 into set 0 ----
    if (t0 < NT) {
        f32x4 vld[3], sld;
#pragma unroll
        for (int j = 0; j < 3; ++j) {
            int c = tid + (j << 9);
            int d = c >> 9, rem = c & 511;
            int row = rem >> 5, c4 = rem & 31;
            vld[j] = *(const f32x4*)(V + (((size_t)((t0 << 4) + row) * 3 + d) << 7) + (c4 << 2));
        }
        { int row = tid >> 5, c4 = tid & 31;
          sld = *(const f32x4*)(S + (((size_t)((t0 << 4) + row)) << 7) + (c4 << 2)); }
#pragma unroll
        for (int j = 0; j < 3; ++j) {
            int c = tid + (j << 9);
            int d = c >> 9, rem = c & 511;
            int row = rem >> 5, c4 = rem & 31;
            *(unsigned long long*)(lds + VIN_OFF + (d << 12) + row * 256 +
                                   ((c4 << 3) ^ ((row & 7) << 4))) = pack4bf(vld[j]);
        }
        { int row = tid >> 5, c4 = tid & 31;
          *(unsigned long long*)(lds + H_OFF + row * 512 +
                                 ((c4 << 3) ^ ((row & 7) << 4))) = pack4bf(sld); }
    }
    __syncthreads();

    int i = 0;
    for (int ty = t0; ty < NT + stride; ty += stride, ++i) {
        const bool yv = (ty < NT);
        const bool xv = (i > 0);
        const int  tz = ty + stride;
        const bool zv = (tz < NT);
        unsigned char* Lsy = lds + (i & 1) * SET_SZ;
        unsigned char* Lsx = lds + ((i & 1) ^ 1) * SET_SZ;

        // ======== slot 1: Y.P1 (L0 v-phase) || X.P4 (L1 v-phase) ; issue Z loads ========
        f32x4 vld[3], sld;
        if (zv) {
#pragma unroll
            for (int j = 0; j < 3; ++j) {
                int c = tid + (j << 9);
                int d = c >> 9, rem = c & 511;
                int row = rem >> 5, c4 = rem & 31;
                vld[j] = *(const f32x4*)(V + (((size_t)((tz << 4) + row) * 3 + d) << 7) + (c4 << 2));
            }
            { int row = tid >> 5, c4 = tid & 31;
              sld = *(const f32x4*)(S + (((size_t)((tz << 4) + row)) << 7) + (c4 << 2)); }
        }

        f32x4 v1a[3];
        if (yv) {
            f32x4 n2 = zero4();
#pragma unroll
            for (int d = 0; d < 3; ++d) {
                f32x4 a1 = zero4(), a2 = zero4();
#pragma unroll
                for (int kt = 0; kt < 4; ++kt) {
                    bf16x8 a = afrag(Lsy + VIN_OFF + (d << 12), 256, l15, (kt << 6) + kbb);
                    a1 = MF(a, uw0f[kt], a1);
                    a2 = MF(a, vw0f[kt], a2);
                }
                v1a[d] = a1;
#pragma unroll
                for (int e = 0; e < 4; ++e) { float x = a2[e] + 1e-8f; n2[e] += x * x; }
            }
#pragma unroll
            for (int e = 0; e < 4; ++e) {
                int row = (lg << 2) + e;
                *(unsigned short*)(Lsy + H_OFF + row * 512 +
                    ((256 + (grow << 1)) ^ ((row & 7) << 4))) = f2bu(sqrtf(n2[e]));
            }
        }
        if (xv) {
            f32x4 n2 = zero4();
#pragma unroll
            for (int d = 0; d < 3; ++d) {
                f32x4 acc = zero4();
#pragma unroll
                for (int kt = 0; kt < 4; ++kt)
                    acc = MF(afrag(Lsx + VIN_OFF + (d << 12), 256, l15, (kt << 6) + kbb),
                             vw1f[kt], acc);
#pragma unroll
                for (int e = 0; e < 4; ++e) { float x = acc[e] + 1e-8f; n2[e] += x * x; }
            }
#pragma unroll
            for (int e = 0; e < 4; ++e) {
                int row = (lg << 2) + e;
                *(unsigned short*)(Lsx + H_OFF + row * 512 +
                    ((256 + (grow << 1)) ^ ((row & 7) << 4))) = f2bu(sqrtf(n2[e]));
            }
        }
        __syncthreads();

        // ======== slot 2: Y.P2 (L0 MLP1) || X.P5 (L1 MLP1 + folded readout) ; write V(Z) ========
        if (yv) {
            f32x4 m = zero4();
#pragma unroll
            for (int kt = 0; kt < 8; ++kt)
                m = MF(afrag(Lsy + H_OFF, 512, l15, (kt << 6) + kbb), w1f0[kt], m);
#pragma unroll
            for (int e = 0; e < 4; ++e) {
                float x = m[e] + b1_0;
                float y = x / (1.f + __expf(-x));
                int row = (lg << 2) + e;
                *(unsigned short*)(lds + S1_OFF + row * 256 +
                    ((grow << 1) ^ ((row & 7) << 4))) = f2bu(y);
            }
        }
        if (xv) {
            f32x4 m = zero4();
#pragma unroll
            for (int kt = 0; kt < 8; ++kt)
                m = MF(afrag(Lsx + H_OFF, 512, l15, (kt << 6) + kbb), w1f1[kt], m);
            float p[4];
#pragma unroll
            for (int e = 0; e < 4; ++e) {
                float x = m[e] + b1_1;
                float y = x / (1.f + __expf(-x));
                p[e] = y * wf;                    // folded (w2g1^T @ outw) readout, f32
            }
#pragma unroll
            for (int off = 1; off < 16; off <<= 1) {
#pragma unroll
                for (int e = 0; e < 4; ++e) p[e] += __shfl_xor(p[e], off);
            }
            if (l15 == 0) {
#pragma unroll
                for (int e = 0; e < 4; ++e)
                    *((float*)(lds + RED_OFF) + (wv << 4) + (lg << 2) + e) = p[e];
            }
        }
        if (zv) {
#pragma unroll
            for (int j = 0; j < 3; ++j) {
                int c = tid + (j << 9);
                int d = c >> 9, rem = c & 511;
                int row = rem >> 5, c4 = rem & 31;
                *(unsigned long long*)(Lsx + VIN_OFF + (d << 12) + row * 256 +
                                       ((c4 << 3) ^ ((row & 7) << 4))) = pack4bf(vld[j]);
            }
        }
        __syncthreads();

        // ======== slot 3: Y.P3 (L0 MLP2 + v'=v1*ss) ; write S(Z) ; sOut(X) ========
        if (yv) {
            f32x4 sg = zero4(), ssa = zero4();
#pragma unroll
            for (int kt = 0; kt < 4; ++kt) {
                bf16x8 a = afrag(lds + S1_OFF, 256, l15, (kt << 6) + kbb);
                sg  = MF(a, w2g0[kt], sg);
                ssa = MF(a, w2s0[kt], ssa);
            }
#pragma unroll
            for (int e = 0; e < 4; ++e) {
                int row = (lg << 2) + e;
                int swz = (row & 7) << 4;
                *(unsigned short*)(Lsy + H_OFF + row * 512 + ((grow << 1) ^ swz)) = f2bu(sg[e] + b2g0);
                float ssv = ssa[e] + b2s0;
#pragma unroll
                for (int d = 0; d < 3; ++d)
                    *(unsigned short*)(Lsy + VIN_OFF + (d << 12) + row * 256 +
                        ((grow << 1) ^ swz)) = f2bu(v1a[d][e] * ssv);
            }
        }
        if (zv) {
            int row = tid >> 5, c4 = tid & 31;
            *(unsigned long long*)(Lsx + H_OFF + row * 512 +
                                   ((c4 << 3) ^ ((row & 7) << 4))) = pack4bf(sld);
        }
        if (xv && tid < 16) {
            float s = 0.f;
#pragma unroll
            for (int w = 0; w < 8; ++w) s += *((float*)(lds + RED_OFF) + (w << 4) + tid);
            sOut[((ty - stride) << 4) + tid] = s + cf;
        }
        __syncthreads();
    }
}

// Dense masked pooling: y[b] = sum_a batch[b,a] * s_out[a]
__global__ __launch_bounds__(256) void eqsc_pool(const float* __restrict__ batch,
                                                 const float* __restrict__ s,
                                                 float* __restrict__ out,
                                                 int NA, int B, int CH)
{
    int b  = blockIdx.x % B;
    int ch = blockIdx.x / B;
    int a0 = ch * CH;
    int a1 = min(a0 + CH, NA);
    const float* br = batch + (size_t)b * NA;
    float acc = 0.f;
    for (int a = a0 + (threadIdx.x << 2); a < a1; a += 256 * 4) {
        f32x4 bb = *(const f32x4*)(br + a);
        f32x4 sv = *(const f32x4*)(s + a);
        acc += bb[0] * sv[0] + bb[1] * sv[1] + bb[2] * sv[2] + bb[3] * sv[3];
    }
#pragma unroll
    for (int off = 32; off > 0; off >>= 1) acc += __shfl_down(acc, off);
    __shared__ float wsum[4];
    if ((threadIdx.x & 63) == 0) wsum[threadIdx.x >> 6] = acc;
    __syncthreads();
    if (threadIdx.x == 0) atomicAdd(&out[b], wsum[0] + wsum[1] + wsum[2] + wsum[3]);
}

extern "C" void kernel_launch(void* const* d_in, const int* in_sizes, int n_in,
                              void* d_out, int out_size, void* d_ws, size_t ws_size,
                              hipStream_t stream)
{
    const float* S     = (const float*)d_in[0];
    const float* V     = (const float*)d_in[1];
    // d_in[2] = pos, unused by the reference
    const float* batch = (const float*)d_in[3];
    const float* u0w   = (const float*)d_in[4];
    const float* v0w   = (const float*)d_in[5];
    const float* a0w1  = (const float*)d_in[6];
    const float* a0b1  = (const float*)d_in[7];
    const float* a0w2  = (const float*)d_in[8];
    const float* a0b2  = (const float*)d_in[9];
    const float* u1w   = (const float*)d_in[10];
    const float* v1w   = (const float*)d_in[11];
    const float* a1w1  = (const float*)d_in[12];
    const float* a1b1  = (const float*)d_in[13];
    const float* a1w2  = (const float*)d_in[14];
    const float* a1b2  = (const float*)d_in[15];
    const float* outw  = (const float*)d_in[16];
    const float* outb  = (const float*)d_in[17];

    const int NA = in_sizes[0] / 128;
    const int NT = NA / 16;                  // 16 atoms per tile
    const int B  = in_sizes[3] / NA;
    float* sAtom = (float*)d_ws;

    hipMemsetAsync(d_out, 0, (size_t)out_size * sizeof(float), stream);

    // grid = 768 = 3 blocks/CU: LDS 3*45.5KB = 136.7 <= 160KB, regs 272/wave * 6
    // waves/SIMD = 1632 <= 2048. Cross-block overlap hides barrier drains (m114).
    eqsc_main<<<768, 512, 0, stream>>>(S, V, u0w, v0w, a0w1, a0b1, a0w2, a0b2,
                                       u1w, v1w, a1w1, a1b1, a1w2, a1b2,
                                       outw, outb, sAtom, NT);

    const int CH  = 16384;
    const int NCH = (NA + CH - 1) / CH;
    eqsc_pool<<<B * NCH, 256, 0, stream>>>(batch, sAtom, (float*)d_out, NA, B, CH);
}